// Round 4
// baseline (79.044 us; speedup 1.0000x reference)
//
#include <hip/hip_runtime.h>
#include <hip/hip_bf16.h>

typedef __attribute__((ext_vector_type(8))) short short8;
typedef __attribute__((ext_vector_type(4))) float f32x4;

#define DIMD 128
#define NSPLIT 32
#define WR 64                // rows per wave
#define ROWS_PER_BLOCK 512   // 8 waves * WR
#define CPS 256              // cols per block (whole split in LDS, 64 KB)

// scale = sqrt(2 * log2(e)) so that acc = (c*zn_i)·(c*zn_j) = 2*log2(e)*cos
// -> exp2(acc) = e^(cos/T) directly, and logit s = acc * ln2.
#define ZSCALE 1.69864363f
#define LN2 0.6931471805599453f

// ---------------- Kernel 1: normalize rows of [z_i; z_j] -> scaled bf16 ------
__global__ __launch_bounds__(256) void nrm_kernel(const float* __restrict__ zi,
                                                  const float* __restrict__ zj,
                                                  __hip_bfloat16* __restrict__ zn,
                                                  float* __restrict__ out, int B) {
  if (blockIdx.x == 0 && threadIdx.x == 0) out[0] = 0.0f;
  int wave = threadIdx.x >> 6, lane = threadIdx.x & 63;
  int N = 2 * B;
  int row = blockIdx.x * 4 + wave;
  if (row >= N) return;
  const float* src = (row < B) ? (zi + (size_t)row * DIMD)
                               : (zj + (size_t)(row - B) * DIMD);
  float2 v = *(const float2*)(src + lane * 2);
  float ss = v.x * v.x + v.y * v.y;
  #pragma unroll
  for (int off = 32; off; off >>= 1) ss += __shfl_xor(ss, off);
  float nrm = sqrtf(ss);
  float r = ZSCALE / fmaxf(nrm, 1e-8f);
  __hip_bfloat16* dst = zn + (size_t)row * DIMD + lane * 2;
  dst[0] = __float2bfloat16(v.x * r);
  dst[1] = __float2bfloat16(v.y * r);
}

// ---------------- Kernel 2: fused zn*zn^T -> sum of exp per row (partial) ----
// grid: (N/512 row-stripes, NSPLIT column splits), block 512 (8 waves).
// Wave owns 64 rows (A in registers). Block stages its ENTIRE 256-col B
// panel into LDS once (64 KB, XOR-swizzled) -> ONE barrier, then a
// barrier-free 16-tile sweep the scheduler can pipeline freely.
__global__ __launch_bounds__(512, 4) void sim_kernel(const __hip_bfloat16* __restrict__ znb,
                                                     float* __restrict__ partial,
                                                     float* __restrict__ pos, int B) {
  const ushort* zn = (const ushort*)znb;
  const int N = 2 * B;
  const int tid = threadIdx.x;
  const int wave = tid >> 6, lane = tid & 63;
  const int l15 = lane & 15, lh = lane >> 4;
  const int R = blockIdx.x * ROWS_PER_BLOCK + wave * WR;
  const int C0 = blockIdx.y * CPS;

  __shared__ ushort lds[CPS * DIMD];  // 64 KB

  // ---- issue B-panel global loads (8 x 16B per thread) ----
  // chunk (r,tid): col = r*32 + (tid>>4), kb = tid&15  (16 threads cover one
  // col's contiguous 256B -> coalesced). LDS slot for (col,kb): kb^(col&7).
  short8 g[8];
  const int scol = tid >> 4, skb = tid & 15;
  #pragma unroll
  for (int r_ = 0; r_ < 8; ++r_) {
    int col = r_ * 32 + scol;
    g[r_] = *(const short8*)(zn + (size_t)(C0 + col) * DIMD + skb * 8);
  }

  // ---- A fragments (issued while B loads are in flight) ----
  // lane l, elems j: A[row = l&15][k = kc*32 + 8*(l>>4) + j]
  short8 a[4][4];
  #pragma unroll
  for (int rg = 0; rg < 4; ++rg) {
    const ushort* ar = zn + (size_t)(R + rg * 16 + l15) * DIMD + lh * 8;
    #pragma unroll
    for (int kc = 0; kc < 4; ++kc) a[rg][kc] = *(const short8*)(ar + kc * 32);
  }

  // ---- write staged B to LDS (swizzled), single barrier ----
  #pragma unroll
  for (int r_ = 0; r_ < 8; ++r_) {
    int col = r_ * 32 + scol;
    *(short8*)(&lds[col * DIMD + ((skb ^ (col & 7)) * 8)]) = g[r_];
  }
  __syncthreads();

  float rs[4][4];
  #pragma unroll
  for (int rg = 0; rg < 4; ++rg)
    #pragma unroll
    for (int r = 0; r < 4; ++r) rs[rg][r] = 0.0f;

  int diagT[4], partT[4];
  #pragma unroll
  for (int rg = 0; rg < 4; ++rg) {
    diagT[rg] = (R + rg * 16) >> 4;
    partT[rg] = ((R + rg * 16 + B) & (N - 1)) >> 4;
  }

  // hoisted swizzled read offsets: (sub*16+l15)&7 == l15&7, constant over sub
  int roff[4];
  #pragma unroll
  for (int kc = 0; kc < 4; ++kc) roff[kc] = ((kc * 4 + lh) ^ (l15 & 7)) * 8;

  #pragma unroll 4
  for (int sub = 0; sub < CPS / 16; ++sub) {
    const ushort* lp = &lds[(sub * 16 + l15) * DIMD];
    short8 bb[4];
    #pragma unroll
    for (int kc = 0; kc < 4; ++kc)
      bb[kc] = *(const short8*)(lp + roff[kc]);
    const int gt = (C0 >> 4) + sub;
    #pragma unroll
    for (int rg = 0; rg < 4; ++rg) {
      f32x4 acc = {0.f, 0.f, 0.f, 0.f};
      acc = __builtin_amdgcn_mfma_f32_16x16x32_bf16(a[rg][0], bb[0], acc, 0, 0, 0);
      acc = __builtin_amdgcn_mfma_f32_16x16x32_bf16(a[rg][1], bb[1], acc, 0, 0, 0);
      acc = __builtin_amdgcn_mfma_f32_16x16x32_bf16(a[rg][2], bb[2], acc, 0, 0, 0);
      acc = __builtin_amdgcn_mfma_f32_16x16x32_bf16(a[rg][3], bb[3], acc, 0, 0, 0);
      if (gt == diagT[rg] || gt == partT[rg]) {
        #pragma unroll
        for (int r = 0; r < 4; ++r) {
          int i_ = R + rg * 16 + lh * 4 + r;     // C/D: row=(lane>>4)*4+reg
          int jg_ = C0 + sub * 16 + l15;         //       col=lane&15
          if (jg_ == ((i_ + B) & (N - 1))) pos[i_] = acc[r] * LN2;
          if (jg_ != i_) rs[rg][r] += __builtin_amdgcn_exp2f(acc[r]);
        }
      } else {
        #pragma unroll
        for (int r = 0; r < 4; ++r)
          rs[rg][r] += __builtin_amdgcn_exp2f(acc[r]);
      }
    }
  }

  // reduce each row's partial across the 16 lanes sharing (lane>>4)
  #pragma unroll
  for (int rg = 0; rg < 4; ++rg) {
    #pragma unroll
    for (int r = 0; r < 4; ++r) {
      #pragma unroll
      for (int off = 1; off < 16; off <<= 1)
        rs[rg][r] += __shfl_xor(rs[rg][r], off);
    }
  }
  if (l15 == 0) {
    #pragma unroll
    for (int rg = 0; rg < 4; ++rg)
      #pragma unroll
      for (int r = 0; r < 4; ++r)
        partial[(size_t)(R + rg * 16 + lh * 4 + r) * NSPLIT + blockIdx.y] = rs[rg][r];
  }
}

// ---------------- Kernel 3: row_loss = log(sum) - pos; mean over rows -------
__global__ __launch_bounds__(256) void fin_kernel(const float* __restrict__ partial,
                                                  const float* __restrict__ pos,
                                                  float* __restrict__ out, int N) {
  int i = blockIdx.x * 256 + threadIdx.x;
  float li = 0.0f;
  if (i < N) {
    float s = 0.0f;
    #pragma unroll
    for (int q = 0; q < NSPLIT; ++q) s += partial[(size_t)i * NSPLIT + q];
    li = __builtin_amdgcn_logf(s) * LN2 - pos[i];
  }
  #pragma unroll
  for (int off = 32; off; off >>= 1) li += __shfl_xor(li, off);
  __shared__ float red[4];
  int wave = threadIdx.x >> 6, lane = threadIdx.x & 63;
  if (lane == 0) red[wave] = li;
  __syncthreads();
  if (threadIdx.x == 0) {
    float bs = red[0] + red[1] + red[2] + red[3];
    atomicAdd(out, bs / (float)N);
  }
}

extern "C" void kernel_launch(void* const* d_in, const int* in_sizes, int n_in,
                              void* d_out, int out_size, void* d_ws, size_t ws_size,
                              hipStream_t stream) {
  const float* zi = (const float*)d_in[0];
  const float* zj = (const float*)d_in[1];
  const int B = in_sizes[0] / DIMD;   // 4096
  const int N = 2 * B;                // 8192
  float* out = (float*)d_out;

  char* ws = (char*)d_ws;
  __hip_bfloat16* zn = (__hip_bfloat16*)ws;                       // N*D*2 bytes
  float* partial = (float*)(ws + (size_t)N * DIMD * 2);           // N*NSPLIT*4
  float* pos = (float*)(ws + (size_t)N * DIMD * 2 + (size_t)N * NSPLIT * 4);

  nrm_kernel<<<N / 4, 256, 0, stream>>>(zi, zj, zn, out, B);
  dim3 g2(N / ROWS_PER_BLOCK, NSPLIT);
  sim_kernel<<<g2, 512, 0, stream>>>(zn, partial, pos, B);
  fin_kernel<<<N / 256, 256, 0, stream>>>(partial, pos, out, N);
}

// Round 5
// 39.151 us; speedup vs baseline: 2.0190x; 2.0190x over previous
//
#include <hip/hip_runtime.h>
#include <hip/hip_bf16.h>

typedef __attribute__((ext_vector_type(8))) short short8;
typedef __attribute__((ext_vector_type(4))) float f32x4;
typedef __attribute__((address_space(1))) const unsigned int glb_u32;
typedef __attribute__((address_space(3))) unsigned int lds_u32;

#define DIMD 128
#define NSPLIT 16
#define WR 64                // rows per wave
#define ROWS_PER_BLOCK 256   // 4 waves * WR
#define CPS 64               // cols per LDS stage

// scale = sqrt(2 * log2(e)) so that acc = (c*zn_i)·(c*zn_j) = 2*log2(e)*cos
// -> exp2(acc) = e^(cos/T) directly, and logit s = acc * ln2.
#define ZSCALE 1.69864363f
#define LN2 0.6931471805599453f

// ---------------- Kernel 1: normalize rows of [z_i; z_j] -> scaled bf16 ------
__global__ __launch_bounds__(256) void nrm_kernel(const float* __restrict__ zi,
                                                  const float* __restrict__ zj,
                                                  __hip_bfloat16* __restrict__ zn,
                                                  float* __restrict__ out, int B) {
  if (blockIdx.x == 0 && threadIdx.x == 0) out[0] = 0.0f;
  int wave = threadIdx.x >> 6, lane = threadIdx.x & 63;
  int N = 2 * B;
  int row = blockIdx.x * 4 + wave;
  if (row >= N) return;
  const float* src = (row < B) ? (zi + (size_t)row * DIMD)
                               : (zj + (size_t)(row - B) * DIMD);
  float2 v = *(const float2*)(src + lane * 2);
  float ss = v.x * v.x + v.y * v.y;
  #pragma unroll
  for (int off = 32; off; off >>= 1) ss += __shfl_xor(ss, off);
  float nrm = sqrtf(ss);
  float r = ZSCALE / fmaxf(nrm, 1e-8f);
  __hip_bfloat16* dst = zn + (size_t)row * DIMD + lane * 2;
  dst[0] = __float2bfloat16(v.x * r);
  dst[1] = __float2bfloat16(v.y * r);
}

// ---------------- Kernel 2: fused zn*zn^T -> sum of exp per row (partial) ----
// grid: (N/256 row-stripes, NSPLIT column splits), block 256 (4 waves).
// Wave owns 64 rows (A in registers). B staged via global_load_lds into a
// double-buffered, XOR-swizzled LDS panel (linear LDS dest + pre-swizzled
// global source, G21). One barrier per stage; next-stage loads issued right
// after the barrier so they drain for free at the following barrier.

// per stage, wave w call c_ covers cols [c_*16 + w*4, +4): wave-uniform LDS
// base, lane i lands at col +(i>>4), 16B slot (i&15). Source pre-swizzled so
// slot kb' holds data k-chunk kb'^(col&7).
#define STAGE(BUF, ST)                                                        \
  {                                                                           \
    const ushort* s_ = gsrc0 + (size_t)(ST) * (CPS * DIMD);                   \
    _Pragma("unroll")                                                         \
    for (int c_ = 0; c_ < 4; ++c_)                                            \
      __builtin_amdgcn_global_load_lds(                                       \
          (glb_u32*)(s_ + c_ * 16 * DIMD),                                    \
          (lds_u32*)&lds[BUF][(c_ * 16 + wave * 4) * DIMD], 16, 0, 0);        \
  }

#define COMPUTE(BUF, CC)                                                      \
  {                                                                           \
    _Pragma("unroll")                                                         \
    for (int sub = 0; sub < 4; ++sub) {                                       \
      const ushort* lp_ = &lds[BUF][(sub * 16 + l15) * DIMD];                 \
      short8 bb[4];                                                           \
      _Pragma("unroll")                                                       \
      for (int kc = 0; kc < 4; ++kc)                                          \
        bb[kc] = *(const short8*)(lp_ + roff[kc]);                            \
      const int gt_ = ((CC) >> 4) + sub;                                      \
      _Pragma("unroll")                                                       \
      for (int rg = 0; rg < 4; ++rg) {                                        \
        f32x4 acc = {0.f, 0.f, 0.f, 0.f};                                     \
        acc = __builtin_amdgcn_mfma_f32_16x16x32_bf16(a[rg][0], bb[0], acc, 0, 0, 0); \
        acc = __builtin_amdgcn_mfma_f32_16x16x32_bf16(a[rg][1], bb[1], acc, 0, 0, 0); \
        acc = __builtin_amdgcn_mfma_f32_16x16x32_bf16(a[rg][2], bb[2], acc, 0, 0, 0); \
        acc = __builtin_amdgcn_mfma_f32_16x16x32_bf16(a[rg][3], bb[3], acc, 0, 0, 0); \
        if (gt_ == diagT[rg] || gt_ == partT[rg]) {                           \
          _Pragma("unroll")                                                   \
          for (int r = 0; r < 4; ++r) {                                       \
            int i_ = R + rg * 16 + lh * 4 + r;   /* C/D: row=(lane>>4)*4+r */ \
            int jg_ = (CC) + sub * 16 + l15;     /*      col=lane&15       */ \
            if (jg_ == ((i_ + B) & (N - 1))) pos[i_] = acc[r] * LN2;          \
            if (jg_ != i_) rs[rg][r] += __builtin_amdgcn_exp2f(acc[r]);       \
          }                                                                   \
        } else {                                                              \
          _Pragma("unroll")                                                   \
          for (int r = 0; r < 4; ++r)                                         \
            rs[rg][r] += __builtin_amdgcn_exp2f(acc[r]);                      \
        }                                                                     \
      }                                                                       \
    }                                                                         \
  }

__global__ __launch_bounds__(256) void sim_kernel(const __hip_bfloat16* __restrict__ znb,
                                                  float* __restrict__ partial,
                                                  float* __restrict__ pos, int B) {
  const ushort* zn = (const ushort*)znb;
  const int N = 2 * B;
  const int tid = threadIdx.x;
  const int wave = tid >> 6, lane = tid & 63;
  const int l15 = lane & 15, lh = lane >> 4;
  const int R = blockIdx.x * ROWS_PER_BLOCK + wave * WR;
  const int colsPerSplit = N / NSPLIT;   // 512
  const int C0 = blockIdx.y * colsPerSplit;
  const int NST = colsPerSplit / CPS;    // 8

  __shared__ ushort lds[2][CPS * DIMD];  // 2 x 16 KB

  // per-lane pre-swizzled staging source (call 0, stage 0). The swizzle term
  // is invariant across calls (+16 cols) and stages (+64 cols): both ≡0 mod 8.
  const int myCol = wave * 4 + lh;
  const int myKb = l15 ^ (myCol & 7);
  const ushort* gsrc0 = zn + (size_t)(C0 + myCol) * DIMD + myKb * 8;

  STAGE(0, 0);  // async: B stage 0 in flight while we load A below

  // A fragments: 4 row-groups x 4 k-chunks, resident all kernel.
  // lane l, elems j: A[row = l&15][k = kc*32 + 8*(l>>4) + j]
  short8 a[4][4];
  #pragma unroll
  for (int rg = 0; rg < 4; ++rg) {
    const ushort* ar = zn + (size_t)(R + rg * 16 + l15) * DIMD + lh * 8;
    #pragma unroll
    for (int kc = 0; kc < 4; ++kc) a[rg][kc] = *(const short8*)(ar + kc * 32);
  }

  float rs[4][4];
  #pragma unroll
  for (int rg = 0; rg < 4; ++rg)
    #pragma unroll
    for (int r = 0; r < 4; ++r) rs[rg][r] = 0.0f;

  int diagT[4], partT[4];
  #pragma unroll
  for (int rg = 0; rg < 4; ++rg) {
    diagT[rg] = (R + rg * 16) >> 4;
    partT[rg] = ((R + rg * 16 + B) & (N - 1)) >> 4;
  }

  // hoisted swizzled read offsets: (sub*16+l15)&7 == l15&7, constant over sub
  int roff[4];
  #pragma unroll
  for (int kc = 0; kc < 4; ++kc) roff[kc] = ((kc * 4 + lh) ^ (l15 & 7)) * 8;

  for (int st = 0; st < NST; ++st) {
    __syncthreads();  // drains stage st's loads (issued a full phase ago)
    if (st + 1 < NST) STAGE((st + 1) & 1, st + 1);  // async next stage
    COMPUTE(st & 1, C0 + st * CPS);
  }

  // reduce each row's partial across the 16 lanes sharing (lane>>4)
  #pragma unroll
  for (int rg = 0; rg < 4; ++rg) {
    #pragma unroll
    for (int r = 0; r < 4; ++r) {
      #pragma unroll
      for (int off = 1; off < 16; off <<= 1)
        rs[rg][r] += __shfl_xor(rs[rg][r], off);
    }
  }
  if (l15 == 0) {
    #pragma unroll
    for (int rg = 0; rg < 4; ++rg)
      #pragma unroll
      for (int r = 0; r < 4; ++r)
        partial[(size_t)(R + rg * 16 + lh * 4 + r) * NSPLIT + blockIdx.y] = rs[rg][r];
  }
}

// ---------------- Kernel 3: row_loss = log(sum) - pos; mean over rows -------
__global__ __launch_bounds__(256) void fin_kernel(const float* __restrict__ partial,
                                                  const float* __restrict__ pos,
                                                  float* __restrict__ out, int N) {
  int i = blockIdx.x * 256 + threadIdx.x;
  float li = 0.0f;
  if (i < N) {
    float s = 0.0f;
    #pragma unroll
    for (int q = 0; q < NSPLIT; ++q) s += partial[(size_t)i * NSPLIT + q];
    li = __builtin_amdgcn_logf(s) * LN2 - pos[i];
  }
  #pragma unroll
  for (int off = 32; off; off >>= 1) li += __shfl_xor(li, off);
  __shared__ float red[4];
  int wave = threadIdx.x >> 6, lane = threadIdx.x & 63;
  if (lane == 0) red[wave] = li;
  __syncthreads();
  if (threadIdx.x == 0) {
    float bs = red[0] + red[1] + red[2] + red[3];
    atomicAdd(out, bs / (float)N);
  }
}

extern "C" void kernel_launch(void* const* d_in, const int* in_sizes, int n_in,
                              void* d_out, int out_size, void* d_ws, size_t ws_size,
                              hipStream_t stream) {
  const float* zi = (const float*)d_in[0];
  const float* zj = (const float*)d_in[1];
  const int B = in_sizes[0] / DIMD;   // 4096
  const int N = 2 * B;                // 8192
  float* out = (float*)d_out;

  char* ws = (char*)d_ws;
  __hip_bfloat16* zn = (__hip_bfloat16*)ws;                       // N*D*2 bytes
  float* partial = (float*)(ws + (size_t)N * DIMD * 2);           // N*NSPLIT*4
  float* pos = (float*)(ws + (size_t)N * DIMD * 2 + (size_t)N * NSPLIT * 4);

  nrm_kernel<<<N / 4, 256, 0, stream>>>(zi, zj, zn, out, B);
  dim3 g2(N / ROWS_PER_BLOCK, NSPLIT);
  sim_kernel<<<g2, 256, 0, stream>>>(zn, partial, pos, B);
  fin_kernel<<<N / 256, 256, 0, stream>>>(partial, pos, out, N);
}